// Round 1
// baseline (3184.413 us; speedup 1.0000x reference)
//
#include <hip/hip_runtime.h>
#include <hip/hip_bf16.h>

#define DIMV   1024
#define NTOK   16384   // B*N
#define NSEQ   8192
#define NHEADS 8
#define INNERV 512
#define HIDV   2730
#define HIDP   2736    // padded leading dim (16B-aligned rows)
#define QKVN   1536

typedef float          f32x4  __attribute__((ext_vector_type(4)));
typedef __bf16         bf16x8 __attribute__((ext_vector_type(8)));
typedef unsigned short u16x8  __attribute__((ext_vector_type(8)));
typedef unsigned short u16x4  __attribute__((ext_vector_type(4)));

static __device__ __forceinline__ unsigned short f2bf(float f) {
  unsigned int u = __builtin_bit_cast(unsigned int, f);
  u = u + 0x7fffu + ((u >> 16) & 1u);           // RNE
  return (unsigned short)(u >> 16);
}
static __device__ __forceinline__ float bf2f(unsigned short h) {
  unsigned int u = ((unsigned int)h) << 16;
  return __builtin_bit_cast(float, u);
}
static __device__ __forceinline__ f32x4 mfma16(bf16x8 a, bf16x8 b, f32x4 c) {
  return __builtin_amdgcn_mfma_f32_16x16x32_bf16(a, b, c, 0, 0, 0);
}
static __device__ __forceinline__ bf16x8 ld_frag_lds(const unsigned short* p) {
  return __builtin_bit_cast(bf16x8, *reinterpret_cast<const u16x8*>(p));
}

// ---------------- weight transpose fp32[R][C] -> bf16[C][ldout] ----------------
__global__ __launch_bounds__(256) void k_transpose(const float* __restrict__ in,
    unsigned short* __restrict__ out, int R, int C, int ldout)
{
  __shared__ unsigned short tile[32][33];
  int c0 = blockIdx.x * 32, r0 = blockIdx.y * 32;
  int tx = threadIdx.x & 31, ty = threadIdx.x >> 5;   // 32x8
  for (int i = ty; i < 32; i += 8) {
    int r = r0 + i, c = c0 + tx;
    tile[i][tx] = (r < R && c < C) ? f2bf(in[(size_t)r * C + c]) : (unsigned short)0;
  }
  __syncthreads();
  for (int i = ty; i < 32; i += 8) {
    int c = c0 + i, r = r0 + tx;
    if (c < C && r < R) out[(size_t)c * ldout + r] = tile[tx][i];
  }
}

// ---------------- shift_token: x fp32 -> h bf16 ----------------
__global__ __launch_bounds__(256) void k_shift(const float* __restrict__ X,
                                               unsigned short* __restrict__ H)
{
  int t = blockIdx.x;
  int n = t & (NSEQ - 1);
  int d0 = threadIdx.x * 4;
  float4 v = make_float4(0.f, 0.f, 0.f, 0.f);
  if (d0 < 512)      v = *reinterpret_cast<const float4*>(X + (size_t)t * DIMV + d0);
  else if (n > 0)    v = *reinterpret_cast<const float4*>(X + (size_t)(t - 1) * DIMV + d0);
  u16x4 o; o[0] = f2bf(v.x); o[1] = f2bf(v.y); o[2] = f2bf(v.z); o[3] = f2bf(v.w);
  *reinterpret_cast<u16x4*>(H + (size_t)t * DIMV + d0) = o;
}

// ---------------- shift_token + LayerNorm: x fp32 -> h bf16 ----------------
__global__ __launch_bounds__(256) void k_ln_shift(const float* __restrict__ X,
    unsigned short* __restrict__ H, const float* __restrict__ G, const float* __restrict__ Bv)
{
  __shared__ float red[8];
  int t = blockIdx.x;
  int n = t & (NSEQ - 1);
  int d0 = threadIdx.x * 4;
  float4 v = make_float4(0.f, 0.f, 0.f, 0.f);
  if (d0 < 512)      v = *reinterpret_cast<const float4*>(X + (size_t)t * DIMV + d0);
  else if (n > 0)    v = *reinterpret_cast<const float4*>(X + (size_t)(t - 1) * DIMV + d0);
  float s1 = v.x + v.y + v.z + v.w;
  float s2 = v.x * v.x + v.y * v.y + v.z * v.z + v.w * v.w;
  #pragma unroll
  for (int m = 1; m < 64; m <<= 1) { s1 += __shfl_xor(s1, m); s2 += __shfl_xor(s2, m); }
  int w = threadIdx.x >> 6;
  if ((threadIdx.x & 63) == 0) { red[w] = s1; red[4 + w] = s2; }
  __syncthreads();
  s1 = red[0] + red[1] + red[2] + red[3];
  s2 = red[4] + red[5] + red[6] + red[7];
  float mu = s1 * (1.0f / 1024.0f);
  float var = s2 * (1.0f / 1024.0f) - mu * mu;
  float rstd = rsqrtf(var + 1e-5f);
  float vv[4] = { v.x, v.y, v.z, v.w };
  u16x4 o;
  #pragma unroll
  for (int j = 0; j < 4; j++) {
    float h = (vv[j] - mu) * rstd * G[d0 + j] + Bv[d0 + j];
    o[j] = f2bf(h);
  }
  *reinterpret_cast<u16x4*>(H + (size_t)t * DIMV + d0) = o;
}

// ---------------- GEMM: C[M,N] = A[M,K] @ Bt[N,K]^T, bf16 in, fp32 acc ----------------
// EPI 0: store bf16 to Cb. EPI 1: dual-tile GEGLU -> Cb. EPI 2: Cf += acc + bias.
template<int EPI>
__global__ __launch_bounds__(256) void k_gemm(
    const unsigned short* __restrict__ A, int lda,
    const unsigned short* __restrict__ Bt, int ldb,
    unsigned short* __restrict__ Cb, float* __restrict__ Cf,
    const float* __restrict__ bias,
    int N, int K, int ldc, int gofs)
{
  constexpr int NB = (EPI == 1) ? 3 : 2;
  __shared__ unsigned short lds[NB * 128 * 56];   // rows padded to 56 (112B, 16B-mult)
  unsigned short* As  = lds;
  unsigned short* Bs  = lds + 128 * 56;
  unsigned short* Bs2 = lds + 2 * 128 * 56;
  int tid = threadIdx.x;
  int m0 = blockIdx.x * 128, n0 = blockIdx.y * 128;
  int wid = tid >> 6, lane = tid & 63;
  int wm = wid >> 1, wn = wid & 1;
  int lm = lane & 15, lg = lane >> 4;

  f32x4 acc[4][4] = {};
  f32x4 acc2[(EPI == 1) ? 4 : 1][(EPI == 1) ? 4 : 1] = {};

  auto stage1 = [&](const unsigned short* src, int srow, int rlim, int ld, int gk,
                    unsigned short* dst) {
    u16x8 val;
    if (srow < rlim && gk + 8 <= K) {
      val = *reinterpret_cast<const u16x8*>(src + (size_t)srow * ld + gk);
    } else {
      #pragma unroll
      for (int j = 0; j < 8; j++)
        val[j] = (srow < rlim && gk + j < K) ? src[(size_t)srow * ld + gk + j]
                                             : (unsigned short)0;
    }
    *reinterpret_cast<u16x8*>(dst) = val;
  };

  int nk = (K + 31) / 32;
  for (int it = 0; it < nk; it++) {
    int k0 = it * 32;
    #pragma unroll
    for (int ci = 0; ci < 2; ci++) {
      int c = tid + ci * 256;
      int row = c >> 2, kk = (c & 3) * 8;
      stage1(A,  m0 + row, 1 << 30, lda, k0 + kk, &As[row * 56 + kk]);
      stage1(Bt, n0 + row, N,       ldb, k0 + kk, &Bs[row * 56 + kk]);
      if constexpr (EPI == 1)
        stage1(Bt, n0 + row + gofs, N + gofs, ldb, k0 + kk, &Bs2[row * 56 + kk]);
    }
    __syncthreads();
    bf16x8 af[4], bfr[4];
    #pragma unroll
    for (int f = 0; f < 4; f++) {
      af[f]  = ld_frag_lds(&As[(wm * 64 + f * 16 + lm) * 56 + lg * 8]);
      bfr[f] = ld_frag_lds(&Bs[(wn * 64 + f * 16 + lm) * 56 + lg * 8]);
    }
    #pragma unroll
    for (int mf = 0; mf < 4; mf++)
      #pragma unroll
      for (int nf = 0; nf < 4; nf++)
        acc[mf][nf] = mfma16(af[mf], bfr[nf], acc[mf][nf]);
    if constexpr (EPI == 1) {
      bf16x8 bg[4];
      #pragma unroll
      for (int f = 0; f < 4; f++)
        bg[f] = ld_frag_lds(&Bs2[(wn * 64 + f * 16 + lm) * 56 + lg * 8]);
      #pragma unroll
      for (int mf = 0; mf < 4; mf++)
        #pragma unroll
        for (int nf = 0; nf < 4; nf++)
          acc2[mf][nf] = mfma16(af[mf], bg[nf], acc2[mf][nf]);
    }
    __syncthreads();
  }

  // epilogue. C/D frag layout: col = lane&15, row = (lane>>4)*4 + reg  [m89]
  #pragma unroll
  for (int mf = 0; mf < 4; mf++) {
    #pragma unroll
    for (int nf = 0; nf < 4; nf++) {
      int col  = n0 + wn * 64 + nf * 16 + lm;
      int rowb = m0 + wm * 64 + mf * 16 + lg * 4;
      if constexpr (EPI == 0) {
        #pragma unroll
        for (int r = 0; r < 4; r++)
          Cb[(size_t)(rowb + r) * ldc + col] = f2bf(acc[mf][nf][r]);
      } else if constexpr (EPI == 1) {
        if (col < N) {
          float ba = bias[col], bg2 = bias[col + gofs];
          #pragma unroll
          for (int r = 0; r < 4; r++) {
            float a = acc[mf][nf][r] + ba;
            float g = acc2[mf][nf][r] + bg2;
            float ge = 0.5f * g * (1.0f + erff(g * 0.70710678118f));
            Cb[(size_t)(rowb + r) * ldc + col] = f2bf(a * ge);
          }
        }
      } else {
        float bb = bias ? bias[col] : 0.0f;
        #pragma unroll
        for (int r = 0; r < 4; r++) {
          size_t idx = (size_t)(rowb + r) * ldc + col;
          Cf[idx] += acc[mf][nf][r] + bb;
        }
      }
    }
  }
}

// ---------------- qkv post: l2norm + scale + xpos rotary + QK_SCALE; V -> [bh][d][n] ----------------
__global__ __launch_bounds__(256) void k_qkv_post(
    const unsigned short* __restrict__ QKV,
    const float* __restrict__ qs, const float* __restrict__ ks,
    unsigned short* __restrict__ Qo, unsigned short* __restrict__ Ko,
    unsigned short* __restrict__ VT)
{
  __shared__ unsigned short vt[64 * 72];
  int ntile = blockIdx.x;
  int bh = blockIdx.y;
  int b = bh >> 3, h = bh & 7;
  int tid = threadIdx.x, w = tid >> 6, d = tid & 63;
  int idx = d & 31;
  float invf = exp2f(-(float)idx * (2.0f / 64.0f) * 13.287712379549449f); // 10000^(-2i/64)
  float base = ((float)(2 * idx) + 25.6f) * (1.0f / 89.6f);
  float lgb = log2f(base);
  float qsd = qs[d], ksd = ks[d];
  for (int itr = 0; itr < 16; itr++) {
    int n = ntile * 64 + w * 16 + itr;
    size_t t = (size_t)b * NSEQ + n;
    const unsigned short* row = QKV + t * QKVN + h * 64;
    float qf = bf2f(row[d]);
    float kf = bf2f(row[512 + d]);
    vt[d * 72 + w * 16 + itr] = row[1024 + d];
    float ssq = qf * qf, ksq = kf * kf;
    #pragma unroll
    for (int m = 1; m < 64; m <<= 1) { ssq += __shfl_xor(ssq, m); ksq += __shfl_xor(ksq, m); }
    float qn = qf / fmaxf(sqrtf(ssq), 1e-12f) * qsd;
    float kn = kf / fmaxf(sqrtf(ksq), 1e-12f) * ksd;
    float fr = (float)n * invf;
    float sn, cs;
    sincosf(fr, &sn, &cs);
    float pw = ((float)n - 4096.0f) * (1.0f / 256.0f);
    float scale = exp2f(lgb * pw);
    float qp = __shfl_xor(qn, 32);
    float kp = __shfl_xor(kn, 32);
    float rq = (d < 32) ? -qp : qp;   // rotate_half
    float rk = (d < 32) ? -kp : kp;
    float qo = (qn * cs + rq * sn) * scale * 8.0f;  // QK_SCALE folded in
    float ko = (kn * cs + rk * sn) / scale;
    size_t outi = ((size_t)bh * NSEQ + n) * 64 + d;
    Qo[outi] = f2bf(qo);
    Ko[outi] = f2bf(ko);
  }
  __syncthreads();
  int r = tid >> 2, c0 = (tid & 3) * 16;
  #pragma unroll
  for (int j = 0; j < 2; j++) {
    u16x8 val = *reinterpret_cast<const u16x8*>(&vt[r * 72 + c0 + j * 8]);
    *reinterpret_cast<u16x8*>(&VT[((size_t)bh * 64 + r) * NSEQ + ntile * 64 + c0 + j * 8]) = val;
  }
}

// ---------------- sliding-window flash attention ----------------
// grid (128 q-blocks of 64, 16 bh); 4 waves x 16 q-rows. KV tiles of 64, 9 per block.
__global__ __launch_bounds__(256) void k_attn(
    const unsigned short* __restrict__ Q, const unsigned short* __restrict__ Kk,
    const unsigned short* __restrict__ Vt, unsigned short* __restrict__ O)
{
  __shared__ unsigned short plds[4 * 16 * 72];
  int blk = blockIdx.x, bh = blockIdx.y;
  int b = bh >> 3, h = bh & 7;
  int tid = threadIdx.x, w = tid >> 6, lane = tid & 63;
  int lm = lane & 15, lg = lane >> 4;
  int q0w = blk * 64 + w * 16;
  const unsigned short* Qb = Q  + (size_t)bh * NSEQ * 64;
  const unsigned short* Kb = Kk + (size_t)bh * NSEQ * 64;
  const unsigned short* Vb = Vt + (size_t)bh * 64 * NSEQ;
  bf16x8 qa[2];
  #pragma unroll
  for (int kk = 0; kk < 2; kk++)
    qa[kk] = ld_frag_lds(&Qb[(size_t)(q0w + lm) * 64 + kk * 32 + lg * 8]);
  f32x4 oacc[4] = {};
  float m4[4], l4[4];
  #pragma unroll
  for (int r = 0; r < 4; r++) { m4[r] = -1e30f; l4[r] = 0.0f; }
  unsigned short* pw_lds = &plds[w * 16 * 72];

  for (int tt = 0; tt < 9; tt++) {
    int j0 = blk * 64 - 512 + tt * 64;
    if (j0 < 0) continue;
    f32x4 s[4] = {};
    #pragma unroll
    for (int kk = 0; kk < 2; kk++) {
      #pragma unroll
      for (int nf = 0; nf < 4; nf++) {
        bf16x8 kb = ld_frag_lds(&Kb[(size_t)(j0 + nf * 16 + lm) * 64 + kk * 32 + lg * 8]);
        s[nf] = mfma16(qa[kk], kb, s[nf]);
      }
    }
    if (tt == 0 || tt == 8) {   // tiles 1..7 are provably unmasked
      #pragma unroll
      for (int nf = 0; nf < 4; nf++) {
        int j = j0 + nf * 16 + lm;
        #pragma unroll
        for (int r = 0; r < 4; r++) {
          int i = q0w + lg * 4 + r;
          if (j > i || j < i - 512) s[nf][r] = -1e30f;
        }
      }
    }
    #pragma unroll
    for (int r = 0; r < 4; r++) {
      float mx = fmaxf(fmaxf(s[0][r], s[1][r]), fmaxf(s[2][r], s[3][r]));
      #pragma unroll
      for (int m = 1; m < 16; m <<= 1) mx = fmaxf(mx, __shfl_xor(mx, m));
      float mn = fmaxf(m4[r], mx);
      float alpha = __expf(m4[r] - mn);
      m4[r] = mn;
      float rs = 0.0f;
      #pragma unroll
      for (int nf = 0; nf < 4; nf++) {
        float p = __expf(s[nf][r] - mn);
        s[nf][r] = p;
        rs += p;
      }
      #pragma unroll
      for (int m = 1; m < 16; m <<= 1) rs += __shfl_xor(rs, m);
      l4[r] = l4[r] * alpha + rs;
      #pragma unroll
      for (int nf = 0; nf < 4; nf++) oacc[nf][r] *= alpha;
    }
    // P (C-layout) -> LDS -> A-layout frags
    #pragma unroll
    for (int nf = 0; nf < 4; nf++)
      #pragma unroll
      for (int r = 0; r < 4; r++)
        pw_lds[(lg * 4 + r) * 72 + nf * 16 + lm] = f2bf(s[nf][r]);
    __syncthreads();   // uniform across waves (j0 depends only on blk,tt)
    #pragma unroll
    for (int kk = 0; kk < 2; kk++) {
      bf16x8 pa = ld_frag_lds(&pw_lds[lm * 72 + kk * 32 + lg * 8]);
      #pragma unroll
      for (int nf = 0; nf < 4; nf++) {
        bf16x8 vb = ld_frag_lds(&Vb[(size_t)(nf * 16 + lm) * NSEQ + j0 + kk * 32 + lg * 8]);
        oacc[nf] = mfma16(pa, vb, oacc[nf]);
      }
    }
    __syncthreads();
  }
  #pragma unroll
  for (int nf = 0; nf < 4; nf++) {
    int d = nf * 16 + lm;
    #pragma unroll
    for (int r = 0; r < 4; r++) {
      int i = q0w + lg * 4 + r;
      size_t t = (size_t)b * NSEQ + i;
      O[t * INNERV + h * 64 + d] = f2bf(oacc[nf][r] / l4[r]);
    }
  }
}

// ---------------- host orchestration ----------------
extern "C" void kernel_launch(void* const* d_in, const int* in_sizes, int n_in,
                              void* d_out, int out_size, void* d_ws, size_t ws_size,
                              hipStream_t stream)
{
  const float* x    = (const float*)d_in[0];
  const float* wqkv = (const float*)d_in[1];
  const float* qsc  = (const float*)d_in[2];
  const float* ksc  = (const float*)d_in[3];
  const float* wo   = (const float*)d_in[4];
  const float* lng  = (const float*)d_in[5];
  const float* lnb  = (const float*)d_in[6];
  const float* w1   = (const float*)d_in[7];
  const float* b1   = (const float*)d_in[8];
  const float* w2   = (const float*)d_in[9];
  const float* b2   = (const float*)d_in[10];
  float* xo = (float*)d_out;
  char* ws = (char*)d_ws;

  unsigned short* hbuf  = (unsigned short*)(ws + 0);           // 32MB  [16384][1024]
  unsigned short* qkv   = (unsigned short*)(ws + 33554432);    // 50MB  [16384][1536]
  unsigned short* qarr  = (unsigned short*)(ws + 83886080);    // 16MB  [bh][n][64]
  unsigned short* karr  = (unsigned short*)(ws + 100663296);   // 16MB
  unsigned short* vtarr = (unsigned short*)(ws + 117440512);   // 16MB  [bh][d][n]
  unsigned short* oarr  = (unsigned short*)(ws + 134217728);   // 16MB  [16384][512]
  unsigned short* mlp   = (unsigned short*)(ws + 33554432);    // 87MB, overlays qkv/q/k/vT (dead)
  unsigned short* wqkvT = (unsigned short*)(ws + 150994944);   // [1536][1024]
  unsigned short* woT   = (unsigned short*)(ws + 154140672);   // [1024][512]
  unsigned short* w1T   = (unsigned short*)(ws + 155189248);   // [5460][1024]
  unsigned short* w2T   = (unsigned short*)(ws + 166371328);   // [1024][2736]

  hipMemcpyAsync(xo, x, (size_t)NTOK * DIMV * sizeof(float), hipMemcpyDeviceToDevice, stream);

  for (int l = 0; l < 2; l++) {
    k_transpose<<<dim3(48, 32),  256, 0, stream>>>(wqkv + (size_t)l * DIMV * QKVN,  wqkvT, DIMV,   QKVN,     DIMV);
    k_transpose<<<dim3(32, 16),  256, 0, stream>>>(wo   + (size_t)l * INNERV * DIMV, woT,  INNERV, DIMV,     INNERV);
    k_transpose<<<dim3(171, 32), 256, 0, stream>>>(w1   + (size_t)l * DIMV * 2 * HIDV, w1T, DIMV,  2 * HIDV, DIMV);
    k_transpose<<<dim3(32, 86),  256, 0, stream>>>(w2   + (size_t)l * HIDV * DIMV,  w2T,  HIDV,   DIMV,     HIDP);

    k_shift<<<NTOK, 256, 0, stream>>>(xo, hbuf);
    k_gemm<0><<<dim3(128, 12), 256, 0, stream>>>(hbuf, DIMV, wqkvT, DIMV, qkv, nullptr, nullptr,
                                                 QKVN, DIMV, QKVN, 0);
    k_qkv_post<<<dim3(128, 16), 256, 0, stream>>>(qkv, qsc + l * 64, ksc + l * 64, qarr, karr, vtarr);
    k_attn<<<dim3(128, 16), 256, 0, stream>>>(qarr, karr, vtarr, oarr);
    k_gemm<2><<<dim3(128, 8), 256, 0, stream>>>(oarr, INNERV, woT, INNERV, nullptr, xo, nullptr,
                                                DIMV, INNERV, DIMV, 0);
    k_ln_shift<<<NTOK, 256, 0, stream>>>(xo, hbuf, lng + l * DIMV, lnb + l * DIMV);
    k_gemm<1><<<dim3(128, 22), 256, 0, stream>>>(hbuf, DIMV, w1T, DIMV, mlp, nullptr,
                                                 b1 + (size_t)l * 2 * HIDV,
                                                 HIDV, DIMV, HIDP, HIDV);
    k_gemm<2><<<dim3(128, 8), 256, 0, stream>>>(mlp, HIDP, w2T, HIDP, nullptr, xo,
                                                b2 + l * DIMV, DIMV, HIDV, DIMV, 0);
  }
}

// Round 2
// 2322.810 us; speedup vs baseline: 1.3709x; 1.3709x over previous
//
#include <hip/hip_runtime.h>
#include <hip/hip_bf16.h>

#define DIMV   1024
#define NTOK   16384   // B*N
#define NSEQ   8192
#define NHEADS 8
#define INNERV 512
#define HIDV   2730
#define HIDP   2816    // padded to 128-multiple (exact GEMM tiles, K%32==0)
#define QKVN   1536

typedef float          f32x4  __attribute__((ext_vector_type(4)));
typedef __bf16         bf16x8 __attribute__((ext_vector_type(8)));
typedef unsigned short u16x8  __attribute__((ext_vector_type(8)));
typedef unsigned short u16x4  __attribute__((ext_vector_type(4)));

static __device__ __forceinline__ unsigned short f2bf(float f) {
  unsigned int u = __builtin_bit_cast(unsigned int, f);
  u = u + 0x7fffu + ((u >> 16) & 1u);           // RNE
  return (unsigned short)(u >> 16);
}
static __device__ __forceinline__ float bf2f(unsigned short h) {
  unsigned int u = ((unsigned int)h) << 16;
  return __builtin_bit_cast(float, u);
}
static __device__ __forceinline__ f32x4 mfma16(bf16x8 a, bf16x8 b, f32x4 c) {
  return __builtin_amdgcn_mfma_f32_16x16x32_bf16(a, b, c, 0, 0, 0);
}
static __device__ __forceinline__ bf16x8 ld_frag_lds(const unsigned short* p) {
  return __builtin_bit_cast(bf16x8, *reinterpret_cast<const u16x8*>(p));
}
// async global->LDS, 16B per lane; LDS dest = wave-uniform base + lane*16
static __device__ __forceinline__ void gload_lds16(const unsigned short* g, unsigned short* l) {
  __builtin_amdgcn_global_load_lds(
      (const __attribute__((address_space(1))) unsigned int*)g,
      (__attribute__((address_space(3))) unsigned int*)l, 16, 0, 0);
}

// ------- weight transpose fp32 in[R][istride] (cols cofs..cofs+C) -> bf16 out[Cpad][ldout], zero-padded -------
__global__ __launch_bounds__(256) void k_transpose(const float* __restrict__ in,
    unsigned short* __restrict__ out, int R, int C, int istride, int cofs,
    int Rpad, int Cpad, int ldout)
{
  __shared__ unsigned short tile[32][33];
  int c0 = blockIdx.x * 32, r0 = blockIdx.y * 32;
  int tx = threadIdx.x & 31, ty = threadIdx.x >> 5;   // 32x8
  for (int i = ty; i < 32; i += 8) {
    int r = r0 + i, c = c0 + tx;
    tile[i][tx] = (r < R && c < C) ? f2bf(in[(size_t)r * istride + cofs + c]) : (unsigned short)0;
  }
  __syncthreads();
  for (int i = ty; i < 32; i += 8) {
    int c = c0 + i, r = r0 + tx;
    if (c < Cpad && r < Rpad) out[(size_t)c * ldout + r] = tile[tx][i];
  }
}

// ---------------- shift_token: x fp32 -> h bf16 ----------------
__global__ __launch_bounds__(256) void k_shift(const float* __restrict__ X,
                                               unsigned short* __restrict__ H)
{
  int t = blockIdx.x;
  int n = t & (NSEQ - 1);
  int d0 = threadIdx.x * 4;
  float4 v = make_float4(0.f, 0.f, 0.f, 0.f);
  if (d0 < 512)      v = *reinterpret_cast<const float4*>(X + (size_t)t * DIMV + d0);
  else if (n > 0)    v = *reinterpret_cast<const float4*>(X + (size_t)(t - 1) * DIMV + d0);
  u16x4 o; o[0] = f2bf(v.x); o[1] = f2bf(v.y); o[2] = f2bf(v.z); o[3] = f2bf(v.w);
  *reinterpret_cast<u16x4*>(H + (size_t)t * DIMV + d0) = o;
}

// ---------------- shift_token + LayerNorm: x fp32 -> h bf16 ----------------
__global__ __launch_bounds__(256) void k_ln_shift(const float* __restrict__ X,
    unsigned short* __restrict__ H, const float* __restrict__ G, const float* __restrict__ Bv)
{
  __shared__ float red[8];
  int t = blockIdx.x;
  int n = t & (NSEQ - 1);
  int d0 = threadIdx.x * 4;
  float4 v = make_float4(0.f, 0.f, 0.f, 0.f);
  if (d0 < 512)      v = *reinterpret_cast<const float4*>(X + (size_t)t * DIMV + d0);
  else if (n > 0)    v = *reinterpret_cast<const float4*>(X + (size_t)(t - 1) * DIMV + d0);
  float s1 = v.x + v.y + v.z + v.w;
  float s2 = v.x * v.x + v.y * v.y + v.z * v.z + v.w * v.w;
  #pragma unroll
  for (int m = 1; m < 64; m <<= 1) { s1 += __shfl_xor(s1, m); s2 += __shfl_xor(s2, m); }
  int w = threadIdx.x >> 6;
  if ((threadIdx.x & 63) == 0) { red[w] = s1; red[4 + w] = s2; }
  __syncthreads();
  s1 = red[0] + red[1] + red[2] + red[3];
  s2 = red[4] + red[5] + red[6] + red[7];
  float mu = s1 * (1.0f / 1024.0f);
  float var = s2 * (1.0f / 1024.0f) - mu * mu;
  float rstd = rsqrtf(var + 1e-5f);
  float vv[4] = { v.x, v.y, v.z, v.w };
  u16x4 o;
  #pragma unroll
  for (int j = 0; j < 4; j++) {
    float h = (vv[j] - mu) * rstd * G[d0 + j] + Bv[d0 + j];
    o[j] = f2bf(h);
  }
  *reinterpret_cast<u16x4*>(H + (size_t)t * DIMV + d0) = o;
}

// ---------------- GEMM (m97 structure): C[M,N] = A[M,K] @ Bt[N,K]^T ----------------
// All dims exact: M%128==0, grid.y*128 == padded N, K%32==0. No bounds checks.
// EPI 0: store bf16 to Cb. EPI 1: dual-tile GEGLU -> Cb (zeros past Nvalid).
// EPI 2: Cf += acc + bias.
template<int EPI>
__global__ __launch_bounds__(256) void k_gemm(
    const unsigned short* __restrict__ A, int lda,
    const unsigned short* __restrict__ Bt, int ldb,
    unsigned short* __restrict__ Cb, float* __restrict__ Cf,
    const float* __restrict__ bias,
    int Nvalid, int K, int ldc, int gofsB, int gofsBias)
{
  constexpr int NB = (EPI == 1) ? 3 : 2;
  __shared__ unsigned short lds[NB * 128 * 32];   // linear: [row][32] 64B rows
  unsigned short* As  = lds;
  unsigned short* Bs  = lds + 4096;
  unsigned short* Bs2 = lds + 8192;
  int tid = threadIdx.x;
  int m0 = blockIdx.x * 128, n0 = blockIdx.y * 128;
  int wid = tid >> 6, lane = tid & 63;
  int wm = wid >> 1, wn = wid & 1;
  int lm = lane & 15, lg = lane >> 4;
  int l4 = lane & 3,  lr = lane >> 2;

  const unsigned short* Ag  = A  + (size_t)(m0 + wid * 16 + lr) * lda + l4 * 8;
  const unsigned short* Bg  = Bt + (size_t)(n0 + wid * 16 + lr) * ldb + l4 * 8;
  const unsigned short* Bg2 = Bt + (size_t)(n0 + gofsB + wid * 16 + lr) * ldb + l4 * 8;
  unsigned short* AsW  = As  + wid * 16 * 32;   // wave-uniform LDS base
  unsigned short* BsW  = Bs  + wid * 16 * 32;
  unsigned short* Bs2W = Bs2 + wid * 16 * 32;

  f32x4 acc[4][4] = {};
  f32x4 acc2[(EPI == 1) ? 4 : 1][(EPI == 1) ? 4 : 1] = {};

  int nk = K >> 5;
  for (int it = 0; it < nk; it++) {
    int k0 = it * 32;
    #pragma unroll
    for (int c = 0; c < 2; c++) {
      gload_lds16(Ag + (size_t)(c * 64) * lda + k0, AsW + c * 2048);
      gload_lds16(Bg + (size_t)(c * 64) * ldb + k0, BsW + c * 2048);
      if constexpr (EPI == 1)
        gload_lds16(Bg2 + (size_t)(c * 64) * ldb + k0, Bs2W + c * 2048);
    }
    __syncthreads();   // compiler drains vmcnt(0) before barrier -> LDS tile ready
    bf16x8 af[4], bfr[4];
    #pragma unroll
    for (int f = 0; f < 4; f++) {
      af[f]  = ld_frag_lds(&As[(wm * 64 + f * 16 + lm) * 32 + lg * 8]);
      bfr[f] = ld_frag_lds(&Bs[(wn * 64 + f * 16 + lm) * 32 + lg * 8]);
    }
    #pragma unroll
    for (int mf = 0; mf < 4; mf++)
      #pragma unroll
      for (int nf = 0; nf < 4; nf++)
        acc[mf][nf] = mfma16(af[mf], bfr[nf], acc[mf][nf]);
    if constexpr (EPI == 1) {
      bf16x8 bg[4];
      #pragma unroll
      for (int f = 0; f < 4; f++)
        bg[f] = ld_frag_lds(&Bs2[(wn * 64 + f * 16 + lm) * 32 + lg * 8]);
      #pragma unroll
      for (int mf = 0; mf < 4; mf++)
        #pragma unroll
        for (int nf = 0; nf < 4; nf++)
          acc2[mf][nf] = mfma16(af[mf], bg[nf], acc2[mf][nf]);
    }
    __syncthreads();
  }

  // epilogue. C/D frag layout: col = lane&15, row = (lane>>4)*4 + reg  [m89]
  #pragma unroll
  for (int mf = 0; mf < 4; mf++) {
    #pragma unroll
    for (int nf = 0; nf < 4; nf++) {
      int col  = n0 + wn * 64 + nf * 16 + lm;
      int rowb = m0 + wm * 64 + mf * 16 + lg * 4;
      if constexpr (EPI == 0) {
        #pragma unroll
        for (int r = 0; r < 4; r++)
          Cb[(size_t)(rowb + r) * ldc + col] = f2bf(acc[mf][nf][r]);
      } else if constexpr (EPI == 1) {
        bool valid = col < Nvalid;
        float ba  = valid ? bias[col] : 0.0f;
        float bg2 = valid ? bias[col + gofsBias] : 0.0f;
        #pragma unroll
        for (int r = 0; r < 4; r++) {
          float a = acc[mf][nf][r] + ba;
          float g = acc2[mf][nf][r] + bg2;
          float ge = 0.5f * g * (1.0f + erff(g * 0.70710678118f));
          Cb[(size_t)(rowb + r) * ldc + col] = valid ? f2bf(a * ge) : (unsigned short)0;
        }
      } else {
        float bb = bias ? bias[col] : 0.0f;
        #pragma unroll
        for (int r = 0; r < 4; r++) {
          size_t idx = (size_t)(rowb + r) * ldc + col;
          Cf[idx] += acc[mf][nf][r] + bb;
        }
      }
    }
  }
}

// ---------------- qkv post: l2norm + scale + xpos rotary + QK_SCALE; V -> [bh][d][n] ----------------
__global__ __launch_bounds__(256) void k_qkv_post(
    const unsigned short* __restrict__ QKV,
    const float* __restrict__ qs, const float* __restrict__ ks,
    unsigned short* __restrict__ Qo, unsigned short* __restrict__ Ko,
    unsigned short* __restrict__ VT)
{
  __shared__ unsigned short vt[64 * 72];
  int ntile = blockIdx.x;
  int bh = blockIdx.y;
  int b = bh >> 3, h = bh & 7;
  int tid = threadIdx.x, w = tid >> 6, d = tid & 63;
  int idx = d & 31;
  float invf = exp2f(-(float)idx * (2.0f / 64.0f) * 13.287712379549449f); // 10000^(-2i/64)
  float base = ((float)(2 * idx) + 25.6f) * (1.0f / 89.6f);
  float lgb = log2f(base);
  float qsd = qs[d], ksd = ks[d];
  for (int itr = 0; itr < 16; itr++) {
    int n = ntile * 64 + w * 16 + itr;
    size_t t = (size_t)b * NSEQ + n;
    const unsigned short* row = QKV + t * QKVN + h * 64;
    float qf = bf2f(row[d]);
    float kf = bf2f(row[512 + d]);
    vt[d * 72 + w * 16 + itr] = row[1024 + d];
    float ssq = qf * qf, ksq = kf * kf;
    #pragma unroll
    for (int m = 1; m < 64; m <<= 1) { ssq += __shfl_xor(ssq, m); ksq += __shfl_xor(ksq, m); }
    float qn = qf / fmaxf(sqrtf(ssq), 1e-12f) * qsd;
    float kn = kf / fmaxf(sqrtf(ksq), 1e-12f) * ksd;
    float fr = (float)n * invf;
    float sn, cs;
    sincosf(fr, &sn, &cs);
    float pw = ((float)n - 4096.0f) * (1.0f / 256.0f);
    float scale = exp2f(lgb * pw);
    float qp = __shfl_xor(qn, 32);
    float kp = __shfl_xor(kn, 32);
    float rq = (d < 32) ? -qp : qp;   // rotate_half
    float rk = (d < 32) ? -kp : kp;
    float qo = (qn * cs + rq * sn) * scale * 8.0f;  // QK_SCALE folded in
    float ko = (kn * cs + rk * sn) / scale;
    size_t outi = ((size_t)bh * NSEQ + n) * 64 + d;
    Qo[outi] = f2bf(qo);
    Ko[outi] = f2bf(ko);
  }
  __syncthreads();
  int r = tid >> 2, c0 = (tid & 3) * 16;
  #pragma unroll
  for (int j = 0; j < 2; j++) {
    u16x8 val = *reinterpret_cast<const u16x8*>(&vt[r * 72 + c0 + j * 8]);
    *reinterpret_cast<u16x8*>(&VT[((size_t)bh * 64 + r) * NSEQ + ntile * 64 + c0 + j * 8]) = val;
  }
}

// ---------------- sliding-window flash attention ----------------
__global__ __launch_bounds__(256) void k_attn(
    const unsigned short* __restrict__ Q, const unsigned short* __restrict__ Kk,
    const unsigned short* __restrict__ Vt, unsigned short* __restrict__ O)
{
  __shared__ unsigned short plds[4 * 16 * 72];
  int blk = blockIdx.x, bh = blockIdx.y;
  int b = bh >> 3, h = bh & 7;
  int tid = threadIdx.x, w = tid >> 6, lane = tid & 63;
  int lm = lane & 15, lg = lane >> 4;
  int q0w = blk * 64 + w * 16;
  const unsigned short* Qb = Q  + (size_t)bh * NSEQ * 64;
  const unsigned short* Kb = Kk + (size_t)bh * NSEQ * 64;
  const unsigned short* Vb = Vt + (size_t)bh * 64 * NSEQ;
  bf16x8 qa[2];
  #pragma unroll
  for (int kk = 0; kk < 2; kk++)
    qa[kk] = ld_frag_lds(&Qb[(size_t)(q0w + lm) * 64 + kk * 32 + lg * 8]);
  f32x4 oacc[4] = {};
  float m4[4], l4[4];
  #pragma unroll
  for (int r = 0; r < 4; r++) { m4[r] = -1e30f; l4[r] = 0.0f; }
  unsigned short* pw_lds = &plds[w * 16 * 72];

  for (int tt = 0; tt < 9; tt++) {
    int j0 = blk * 64 - 512 + tt * 64;
    if (j0 < 0) continue;
    f32x4 s[4] = {};
    #pragma unroll
    for (int kk = 0; kk < 2; kk++) {
      #pragma unroll
      for (int nf = 0; nf < 4; nf++) {
        bf16x8 kb = ld_frag_lds(&Kb[(size_t)(j0 + nf * 16 + lm) * 64 + kk * 32 + lg * 8]);
        s[nf] = mfma16(qa[kk], kb, s[nf]);
      }
    }
    if (tt == 0 || tt == 8) {   // tiles 1..7 are provably unmasked
      #pragma unroll
      for (int nf = 0; nf < 4; nf++) {
        int j = j0 + nf * 16 + lm;
        #pragma unroll
        for (int r = 0; r < 4; r++) {
          int i = q0w + lg * 4 + r;
          if (j > i || j < i - 512) s[nf][r] = -1e30f;
        }
      }
    }
    #pragma unroll
    for (int r = 0; r < 4; r++) {
      float mx = fmaxf(fmaxf(s[0][r], s[1][r]), fmaxf(s[2][r], s[3][r]));
      #pragma unroll
      for (int m = 1; m < 16; m <<= 1) mx = fmaxf(mx, __shfl_xor(mx, m));
      float mn = fmaxf(m4[r], mx);
      float alpha = __expf(m4[r] - mn);
      m4[r] = mn;
      float rs = 0.0f;
      #pragma unroll
      for (int nf = 0; nf < 4; nf++) {
        float p = __expf(s[nf][r] - mn);
        s[nf][r] = p;
        rs += p;
      }
      #pragma unroll
      for (int m = 1; m < 16; m <<= 1) rs += __shfl_xor(rs, m);
      l4[r] = l4[r] * alpha + rs;
      #pragma unroll
      for (int nf = 0; nf < 4; nf++) oacc[nf][r] *= alpha;
    }
    #pragma unroll
    for (int nf = 0; nf < 4; nf++)
      #pragma unroll
      for (int r = 0; r < 4; r++)
        pw_lds[(lg * 4 + r) * 72 + nf * 16 + lm] = f2bf(s[nf][r]);
    __syncthreads();
    #pragma unroll
    for (int kk = 0; kk < 2; kk++) {
      bf16x8 pa = ld_frag_lds(&pw_lds[lm * 72 + kk * 32 + lg * 8]);
      #pragma unroll
      for (int nf = 0; nf < 4; nf++) {
        bf16x8 vb = ld_frag_lds(&Vb[(size_t)(nf * 16 + lm) * NSEQ + j0 + kk * 32 + lg * 8]);
        oacc[nf] = mfma16(pa, vb, oacc[nf]);
      }
    }
    __syncthreads();
  }
  #pragma unroll
  for (int nf = 0; nf < 4; nf++) {
    int d = nf * 16 + lm;
    #pragma unroll
    for (int r = 0; r < 4; r++) {
      int i = q0w + lg * 4 + r;
      size_t t = (size_t)b * NSEQ + i;
      O[t * INNERV + h * 64 + d] = f2bf(oacc[nf][r] / l4[r]);
    }
  }
}

// ---------------- host orchestration ----------------
extern "C" void kernel_launch(void* const* d_in, const int* in_sizes, int n_in,
                              void* d_out, int out_size, void* d_ws, size_t ws_size,
                              hipStream_t stream)
{
  const float* x    = (const float*)d_in[0];
  const float* wqkv = (const float*)d_in[1];
  const float* qsc  = (const float*)d_in[2];
  const float* ksc  = (const float*)d_in[3];
  const float* wo   = (const float*)d_in[4];
  const float* lng  = (const float*)d_in[5];
  const float* lnb  = (const float*)d_in[6];
  const float* w1   = (const float*)d_in[7];
  const float* b1   = (const float*)d_in[8];
  const float* w2   = (const float*)d_in[9];
  const float* b2   = (const float*)d_in[10];
  float* xo = (float*)d_out;
  char* ws = (char*)d_ws;

  // layout (oarr overlays hbuf; mlp overlays qkv..vtarr; all lifetime-disjoint)
  unsigned short* hbuf  = (unsigned short*)(ws + 0);           // 32MB [16384][1024]
  unsigned short* oarr  = (unsigned short*)(ws + 0);           // 16MB [16384][512] (hbuf dead)
  unsigned short* qkv   = (unsigned short*)(ws + 33554432);    // 48MB [16384][1536]
  unsigned short* qarr  = (unsigned short*)(ws + 83886080);    // 16MB [bh][n][64]
  unsigned short* karr  = (unsigned short*)(ws + 100663296);   // 16MB
  unsigned short* vtarr = (unsigned short*)(ws + 117440512);   // 16MB [bh][d][n]
  unsigned short* mlp   = (unsigned short*)(ws + 33554432);    // 88MB [16384][2816] (q/k/v dead)
  unsigned short* wqkvT = (unsigned short*)(ws + 134217728);   // [1536][1024]
  unsigned short* woT   = (unsigned short*)(ws + 137363456);   // [1024][512]
  unsigned short* w1T   = (unsigned short*)(ws + 138412032);   // [2*2816][1024] a|gate halves
  unsigned short* w2T   = (unsigned short*)(ws + 149946368);   // [1024][2816] zero-padded K

  hipMemcpyAsync(xo, x, (size_t)NTOK * DIMV * sizeof(float), hipMemcpyDeviceToDevice, stream);

  for (int l = 0; l < 2; l++) {
    const float* w1l = w1 + (size_t)l * DIMV * 2 * HIDV;
    k_transpose<<<dim3(48, 32), 256, 0, stream>>>(wqkv + (size_t)l * DIMV * QKVN, wqkvT,
                                                  DIMV, QKVN, QKVN, 0, DIMV, QKVN, DIMV);
    k_transpose<<<dim3(32, 16), 256, 0, stream>>>(wo + (size_t)l * INNERV * DIMV, woT,
                                                  INNERV, DIMV, DIMV, 0, INNERV, DIMV, INNERV);
    k_transpose<<<dim3(88, 32), 256, 0, stream>>>(w1l, w1T,
                                                  DIMV, HIDV, 2 * HIDV, 0, DIMV, HIDP, DIMV);
    k_transpose<<<dim3(88, 32), 256, 0, stream>>>(w1l, w1T + (size_t)HIDP * DIMV,
                                                  DIMV, HIDV, 2 * HIDV, HIDV, DIMV, HIDP, DIMV);
    k_transpose<<<dim3(32, 88), 256, 0, stream>>>(w2 + (size_t)l * HIDV * DIMV, w2T,
                                                  HIDV, DIMV, DIMV, 0, HIDP, DIMV, HIDP);

    k_shift<<<NTOK, 256, 0, stream>>>(xo, hbuf);
    k_gemm<0><<<dim3(128, 12), 256, 0, stream>>>(hbuf, DIMV, wqkvT, DIMV, qkv, nullptr, nullptr,
                                                 QKVN, DIMV, QKVN, 0, 0);
    k_qkv_post<<<dim3(128, 16), 256, 0, stream>>>(qkv, qsc + l * 64, ksc + l * 64, qarr, karr, vtarr);
    k_attn<<<dim3(128, 16), 256, 0, stream>>>(qarr, karr, vtarr, oarr);
    k_gemm<2><<<dim3(128, 8), 256, 0, stream>>>(oarr, INNERV, woT, INNERV, nullptr, xo, nullptr,
                                                DIMV, INNERV, DIMV, 0, 0);
    k_ln_shift<<<NTOK, 256, 0, stream>>>(xo, hbuf, lng + l * DIMV, lnb + l * DIMV);
    k_gemm<1><<<dim3(128, 22), 256, 0, stream>>>(hbuf, DIMV, w1T, DIMV, mlp, nullptr,
                                                 b1 + (size_t)l * 2 * HIDV,
                                                 HIDV, DIMV, HIDP, HIDP, HIDV);
    k_gemm<2><<<dim3(128, 8), 256, 0, stream>>>(mlp, HIDP, w2T, HIDP, nullptr, xo,
                                                b2 + (size_t)l * DIMV, DIMV, HIDP, DIMV, 0, 0);
  }
}

// Round 3
// 2089.067 us; speedup vs baseline: 1.5243x; 1.1119x over previous
//
#include <hip/hip_runtime.h>
#include <hip/hip_bf16.h>

#define DIMV   1024
#define NTOK   16384   // B*N
#define NSEQ   8192
#define NHEADS 8
#define INNERV 512
#define HIDV   2730
#define HIDP   2816    // padded to 128-multiple (exact GEMM tiles, K%32==0)
#define QKVN   1536

typedef float          f32x4  __attribute__((ext_vector_type(4)));
typedef __bf16         bf16x8 __attribute__((ext_vector_type(8)));
typedef unsigned short u16x8  __attribute__((ext_vector_type(8)));
typedef unsigned short u16x4  __attribute__((ext_vector_type(4)));

static __device__ __forceinline__ unsigned short f2bf(float f) {
  unsigned int u = __builtin_bit_cast(unsigned int, f);
  u = u + 0x7fffu + ((u >> 16) & 1u);           // RNE
  return (unsigned short)(u >> 16);
}
static __device__ __forceinline__ float bf2f(unsigned short h) {
  unsigned int u = ((unsigned int)h) << 16;
  return __builtin_bit_cast(float, u);
}
static __device__ __forceinline__ f32x4 mfma16(bf16x8 a, bf16x8 b, f32x4 c) {
  return __builtin_amdgcn_mfma_f32_16x16x32_bf16(a, b, c, 0, 0, 0);
}
static __device__ __forceinline__ bf16x8 ld_frag_lds(const unsigned short* p) {
  return __builtin_bit_cast(bf16x8, *reinterpret_cast<const u16x8*>(p));
}
// async global->LDS, 16B per lane; LDS dest = wave-uniform base + lane*16
static __device__ __forceinline__ void gload_lds16(const unsigned short* g, unsigned short* l) {
  __builtin_amdgcn_global_load_lds(
      (const __attribute__((address_space(1))) unsigned int*)g,
      (__attribute__((address_space(3))) unsigned int*)l, 16, 0, 0);
}

// ------- weight transpose fp32 in[R][istride] (cols cofs..cofs+C) -> bf16 out[Cpad][ldout], zero-padded -------
__global__ __launch_bounds__(256) void k_transpose(const float* __restrict__ in,
    unsigned short* __restrict__ out, int R, int C, int istride, int cofs,
    int Rpad, int Cpad, int ldout)
{
  __shared__ unsigned short tile[32][33];
  int c0 = blockIdx.x * 32, r0 = blockIdx.y * 32;
  int tx = threadIdx.x & 31, ty = threadIdx.x >> 5;   // 32x8
  for (int i = ty; i < 32; i += 8) {
    int r = r0 + i, c = c0 + tx;
    tile[i][tx] = (r < R && c < C) ? f2bf(in[(size_t)r * istride + cofs + c]) : (unsigned short)0;
  }
  __syncthreads();
  for (int i = ty; i < 32; i += 8) {
    int c = c0 + i, r = r0 + tx;
    if (c < Cpad && r < Rpad) out[(size_t)c * ldout + r] = tile[tx][i];
  }
}

// ---------------- shift_token: x fp32 -> h bf16 ----------------
__global__ __launch_bounds__(256) void k_shift(const float* __restrict__ X,
                                               unsigned short* __restrict__ H)
{
  int t = blockIdx.x;
  int n = t & (NSEQ - 1);
  int d0 = threadIdx.x * 4;
  float4 v = make_float4(0.f, 0.f, 0.f, 0.f);
  if (d0 < 512)      v = *reinterpret_cast<const float4*>(X + (size_t)t * DIMV + d0);
  else if (n > 0)    v = *reinterpret_cast<const float4*>(X + (size_t)(t - 1) * DIMV + d0);
  u16x4 o; o[0] = f2bf(v.x); o[1] = f2bf(v.y); o[2] = f2bf(v.z); o[3] = f2bf(v.w);
  *reinterpret_cast<u16x4*>(H + (size_t)t * DIMV + d0) = o;
}

// ---------------- shift_token + LayerNorm: x fp32 -> h bf16 ----------------
__global__ __launch_bounds__(256) void k_ln_shift(const float* __restrict__ X,
    unsigned short* __restrict__ H, const float* __restrict__ G, const float* __restrict__ Bv)
{
  __shared__ float red[8];
  int t = blockIdx.x;
  int n = t & (NSEQ - 1);
  int d0 = threadIdx.x * 4;
  float4 v = make_float4(0.f, 0.f, 0.f, 0.f);
  if (d0 < 512)      v = *reinterpret_cast<const float4*>(X + (size_t)t * DIMV + d0);
  else if (n > 0)    v = *reinterpret_cast<const float4*>(X + (size_t)(t - 1) * DIMV + d0);
  float s1 = v.x + v.y + v.z + v.w;
  float s2 = v.x * v.x + v.y * v.y + v.z * v.z + v.w * v.w;
  #pragma unroll
  for (int m = 1; m < 64; m <<= 1) { s1 += __shfl_xor(s1, m); s2 += __shfl_xor(s2, m); }
  int w = threadIdx.x >> 6;
  if ((threadIdx.x & 63) == 0) { red[w] = s1; red[4 + w] = s2; }
  __syncthreads();
  s1 = red[0] + red[1] + red[2] + red[3];
  s2 = red[4] + red[5] + red[6] + red[7];
  float mu = s1 * (1.0f / 1024.0f);
  float var = s2 * (1.0f / 1024.0f) - mu * mu;
  float rstd = rsqrtf(var + 1e-5f);
  float vv[4] = { v.x, v.y, v.z, v.w };
  u16x4 o;
  #pragma unroll
  for (int j = 0; j < 4; j++) {
    float h = (vv[j] - mu) * rstd * G[d0 + j] + Bv[d0 + j];
    o[j] = f2bf(h);
  }
  *reinterpret_cast<u16x4*>(H + (size_t)t * DIMV + d0) = o;
}

// ---------------- GEMM (m97 structure): C[M,N] = A[M,K] @ Bt[N,K]^T ----------------
// All dims exact: M%128==0, grid.y*128 == padded N, K%32==0. No bounds checks in loop.
// EPI 0: store bf16 to Cb.
// EPI 2: Cf += acc + bias (fp32 residual).
// EPI 3: store bf16 (acc + bias) to Cb            [GEGLU gate half]
// EPI 4: g = Cb[..]; Cb[..] = (acc+bias)*gelu(g)  [GEGLU a half, in-place combine]
template<int EPI>
__global__ __launch_bounds__(256) void k_gemm(
    const unsigned short* __restrict__ A, int lda,
    const unsigned short* __restrict__ Bt, int ldb,
    unsigned short* __restrict__ Cb, float* __restrict__ Cf,
    const float* __restrict__ bias,
    int Nvalid, int K, int ldc)
{
  __shared__ unsigned short lds[2 * 128 * 32];   // linear: [row][32] 64B rows
  unsigned short* As = lds;
  unsigned short* Bs = lds + 4096;
  int tid = threadIdx.x;
  int m0 = blockIdx.x * 128, n0 = blockIdx.y * 128;
  int wid = tid >> 6, lane = tid & 63;
  int wm = wid >> 1, wn = wid & 1;
  int lm = lane & 15, lg = lane >> 4;
  int l4 = lane & 3,  lr = lane >> 2;

  const unsigned short* Ag = A  + (size_t)(m0 + wid * 16 + lr) * lda + l4 * 8;
  const unsigned short* Bg = Bt + (size_t)(n0 + wid * 16 + lr) * ldb + l4 * 8;
  unsigned short* AsW = As + wid * 16 * 32;   // wave-uniform LDS base
  unsigned short* BsW = Bs + wid * 16 * 32;

  f32x4 acc[4][4] = {};

  int nk = K >> 5;
  for (int it = 0; it < nk; it++) {
    int k0 = it * 32;
    #pragma unroll
    for (int c = 0; c < 2; c++) {
      gload_lds16(Ag + (size_t)(c * 64) * lda + k0, AsW + c * 2048);
      gload_lds16(Bg + (size_t)(c * 64) * ldb + k0, BsW + c * 2048);
    }
    __syncthreads();
    bf16x8 af[4], bfr[4];
    #pragma unroll
    for (int f = 0; f < 4; f++) {
      af[f]  = ld_frag_lds(&As[(wm * 64 + f * 16 + lm) * 32 + lg * 8]);
      bfr[f] = ld_frag_lds(&Bs[(wn * 64 + f * 16 + lm) * 32 + lg * 8]);
    }
    #pragma unroll
    for (int mf = 0; mf < 4; mf++)
      #pragma unroll
      for (int nf = 0; nf < 4; nf++)
        acc[mf][nf] = mfma16(af[mf], bfr[nf], acc[mf][nf]);
    __syncthreads();
  }

  // epilogue. C/D frag layout: col = lane&15, row = (lane>>4)*4 + reg  [m89]
  #pragma unroll
  for (int mf = 0; mf < 4; mf++) {
    #pragma unroll
    for (int nf = 0; nf < 4; nf++) {
      int col  = n0 + wn * 64 + nf * 16 + lm;
      int rowb = m0 + wm * 64 + mf * 16 + lg * 4;
      if constexpr (EPI == 0) {
        #pragma unroll
        for (int r = 0; r < 4; r++)
          Cb[(size_t)(rowb + r) * ldc + col] = f2bf(acc[mf][nf][r]);
      } else if constexpr (EPI == 2) {
        float bb = bias ? bias[col] : 0.0f;
        #pragma unroll
        for (int r = 0; r < 4; r++) {
          size_t idx = (size_t)(rowb + r) * ldc + col;
          Cf[idx] += acc[mf][nf][r] + bb;
        }
      } else if constexpr (EPI == 3) {
        float bb = (col < Nvalid) ? bias[col] : 0.0f;
        #pragma unroll
        for (int r = 0; r < 4; r++)
          Cb[(size_t)(rowb + r) * ldc + col] = f2bf(acc[mf][nf][r] + bb);
      } else {   // EPI == 4
        float bb = (col < Nvalid) ? bias[col] : 0.0f;
        #pragma unroll
        for (int r = 0; r < 4; r++) {
          size_t idx = (size_t)(rowb + r) * ldc + col;
          float g = bf2f(Cb[idx]);
          float ge = 0.5f * g * (1.0f + erff(g * 0.70710678118f));
          Cb[idx] = f2bf((acc[mf][nf][r] + bb) * ge);
        }
      }
    }
  }
}

// ---------------- qkv post: l2norm + scale + xpos rotary + QK_SCALE; V -> [bh][d][n] ----------------
__global__ __launch_bounds__(256) void k_qkv_post(
    const unsigned short* __restrict__ QKV,
    const float* __restrict__ qs, const float* __restrict__ ks,
    unsigned short* __restrict__ Qo, unsigned short* __restrict__ Ko,
    unsigned short* __restrict__ VT)
{
  __shared__ unsigned short vt[64 * 72];
  int ntile = blockIdx.x;
  int bh = blockIdx.y;
  int b = bh >> 3, h = bh & 7;
  int tid = threadIdx.x, w = tid >> 6, d = tid & 63;
  int idx = d & 31;
  float invf = exp2f(-(float)idx * (2.0f / 64.0f) * 13.287712379549449f); // 10000^(-2i/64)
  float base = ((float)(2 * idx) + 25.6f) * (1.0f / 89.6f);
  float lgb = log2f(base);
  float qsd = qs[d], ksd = ks[d];
  for (int itr = 0; itr < 16; itr++) {
    int n = ntile * 64 + w * 16 + itr;
    size_t t = (size_t)b * NSEQ + n;
    const unsigned short* row = QKV + t * QKVN + h * 64;
    float qf = bf2f(row[d]);
    float kf = bf2f(row[512 + d]);
    vt[d * 72 + w * 16 + itr] = row[1024 + d];
    float ssq = qf * qf, ksq = kf * kf;
    #pragma unroll
    for (int m = 1; m < 64; m <<= 1) { ssq += __shfl_xor(ssq, m); ksq += __shfl_xor(ksq, m); }
    float qn = qf / fmaxf(sqrtf(ssq), 1e-12f) * qsd;
    float kn = kf / fmaxf(sqrtf(ksq), 1e-12f) * ksd;
    float fr = (float)n * invf;
    float sn, cs;
    sincosf(fr, &sn, &cs);
    float pw = ((float)n - 4096.0f) * (1.0f / 256.0f);
    float scale = exp2f(lgb * pw);
    float qp = __shfl_xor(qn, 32);
    float kp = __shfl_xor(kn, 32);
    float rq = (d < 32) ? -qp : qp;   // rotate_half
    float rk = (d < 32) ? -kp : kp;
    float qo = (qn * cs + rq * sn) * scale * 8.0f;  // QK_SCALE folded in
    float ko = (kn * cs + rk * sn) / scale;
    size_t outi = ((size_t)bh * NSEQ + n) * 64 + d;
    Qo[outi] = f2bf(qo);
    Ko[outi] = f2bf(ko);
  }
  __syncthreads();
  int r = tid >> 2, c0 = (tid & 3) * 16;
  #pragma unroll
  for (int j = 0; j < 2; j++) {
    u16x8 val = *reinterpret_cast<const u16x8*>(&vt[r * 72 + c0 + j * 8]);
    *reinterpret_cast<u16x8*>(&VT[((size_t)bh * 64 + r) * NSEQ + ntile * 64 + c0 + j * 8]) = val;
  }
}

// ---------------- sliding-window flash attention ----------------
__global__ __launch_bounds__(256) void k_attn(
    const unsigned short* __restrict__ Q, const unsigned short* __restrict__ Kk,
    const unsigned short* __restrict__ Vt, unsigned short* __restrict__ O)
{
  __shared__ unsigned short plds[4 * 16 * 72];
  int blk = blockIdx.x, bh = blockIdx.y;
  int b = bh >> 3, h = bh & 7;
  int tid = threadIdx.x, w = tid >> 6, lane = tid & 63;
  int lm = lane & 15, lg = lane >> 4;
  int q0w = blk * 64 + w * 16;
  const unsigned short* Qb = Q  + (size_t)bh * NSEQ * 64;
  const unsigned short* Kb = Kk + (size_t)bh * NSEQ * 64;
  const unsigned short* Vb = Vt + (size_t)bh * 64 * NSEQ;
  bf16x8 qa[2];
  #pragma unroll
  for (int kk = 0; kk < 2; kk++)
    qa[kk] = ld_frag_lds(&Qb[(size_t)(q0w + lm) * 64 + kk * 32 + lg * 8]);
  f32x4 oacc[4] = {};
  float m4[4], l4[4];
  #pragma unroll
  for (int r = 0; r < 4; r++) { m4[r] = -1e30f; l4[r] = 0.0f; }
  unsigned short* pw_lds = &plds[w * 16 * 72];

  for (int tt = 0; tt < 9; tt++) {
    int j0 = blk * 64 - 512 + tt * 64;
    if (j0 < 0) continue;
    f32x4 s[4] = {};
    #pragma unroll
    for (int kk = 0; kk < 2; kk++) {
      #pragma unroll
      for (int nf = 0; nf < 4; nf++) {
        bf16x8 kb = ld_frag_lds(&Kb[(size_t)(j0 + nf * 16 + lm) * 64 + kk * 32 + lg * 8]);
        s[nf] = mfma16(qa[kk], kb, s[nf]);
      }
    }
    if (tt == 0 || tt == 8) {   // tiles 1..7 are provably unmasked
      #pragma unroll
      for (int nf = 0; nf < 4; nf++) {
        int j = j0 + nf * 16 + lm;
        #pragma unroll
        for (int r = 0; r < 4; r++) {
          int i = q0w + lg * 4 + r;
          if (j > i || j < i - 512) s[nf][r] = -1e30f;
        }
      }
    }
    #pragma unroll
    for (int r = 0; r < 4; r++) {
      float mx = fmaxf(fmaxf(s[0][r], s[1][r]), fmaxf(s[2][r], s[3][r]));
      #pragma unroll
      for (int m = 1; m < 16; m <<= 1) mx = fmaxf(mx, __shfl_xor(mx, m));
      float mn = fmaxf(m4[r], mx);
      float alpha = __expf(m4[r] - mn);
      m4[r] = mn;
      float rs = 0.0f;
      #pragma unroll
      for (int nf = 0; nf < 4; nf++) {
        float p = __expf(s[nf][r] - mn);
        s[nf][r] = p;
        rs += p;
      }
      #pragma unroll
      for (int m = 1; m < 16; m <<= 1) rs += __shfl_xor(rs, m);
      l4[r] = l4[r] * alpha + rs;
      #pragma unroll
      for (int nf = 0; nf < 4; nf++) oacc[nf][r] *= alpha;
    }
    #pragma unroll
    for (int nf = 0; nf < 4; nf++)
      #pragma unroll
      for (int r = 0; r < 4; r++)
        pw_lds[(lg * 4 + r) * 72 + nf * 16 + lm] = f2bf(s[nf][r]);
    __syncthreads();
    #pragma unroll
    for (int kk = 0; kk < 2; kk++) {
      bf16x8 pa = ld_frag_lds(&pw_lds[lm * 72 + kk * 32 + lg * 8]);
      #pragma unroll
      for (int nf = 0; nf < 4; nf++) {
        bf16x8 vb = ld_frag_lds(&Vb[(size_t)(nf * 16 + lm) * NSEQ + j0 + kk * 32 + lg * 8]);
        oacc[nf] = mfma16(pa, vb, oacc[nf]);
      }
    }
    __syncthreads();
  }
  #pragma unroll
  for (int nf = 0; nf < 4; nf++) {
    int d = nf * 16 + lm;
    #pragma unroll
    for (int r = 0; r < 4; r++) {
      int i = q0w + lg * 4 + r;
      size_t t = (size_t)b * NSEQ + i;
      O[t * INNERV + h * 64 + d] = f2bf(oacc[nf][r] / l4[r]);
    }
  }
}

// ---------------- host orchestration ----------------
extern "C" void kernel_launch(void* const* d_in, const int* in_sizes, int n_in,
                              void* d_out, int out_size, void* d_ws, size_t ws_size,
                              hipStream_t stream)
{
  const float* x    = (const float*)d_in[0];
  const float* wqkv = (const float*)d_in[1];
  const float* qsc  = (const float*)d_in[2];
  const float* ksc  = (const float*)d_in[3];
  const float* wo   = (const float*)d_in[4];
  const float* lng  = (const float*)d_in[5];
  const float* lnb  = (const float*)d_in[6];
  const float* w1   = (const float*)d_in[7];
  const float* b1   = (const float*)d_in[8];
  const float* w2   = (const float*)d_in[9];
  const float* b2   = (const float*)d_in[10];
  float* xo = (float*)d_out;
  char* ws = (char*)d_ws;

  // layout (oarr overlays hbuf; mlpG overlays qkv..vtarr; all lifetime-disjoint)
  unsigned short* hbuf  = (unsigned short*)(ws + 0);           // 32MB [16384][1024]
  unsigned short* oarr  = (unsigned short*)(ws + 0);           // 16MB [16384][512] (hbuf dead)
  unsigned short* qkv   = (unsigned short*)(ws + 33554432);    // 48MB [16384][1536]
  unsigned short* qarr  = (unsigned short*)(ws + 83886080);    // 16MB [bh][n][64]
  unsigned short* karr  = (unsigned short*)(ws + 100663296);   // 16MB
  unsigned short* vtarr = (unsigned short*)(ws + 117440512);   // 16MB [bh][d][n]
  unsigned short* mlpG  = (unsigned short*)(ws + 33554432);    // 88MB [16384][2816] (q/k/v dead)
  unsigned short* wqkvT = (unsigned short*)(ws + 134217728);   // [1536][1024]
  unsigned short* woT   = (unsigned short*)(ws + 137363456);   // [1024][512]
  unsigned short* w1T   = (unsigned short*)(ws + 138412032);   // [2*2816][1024] a|gate halves
  unsigned short* w2T   = (unsigned short*)(ws + 149946368);   // [1024][2816] zero-padded K

  hipMemcpyAsync(xo, x, (size_t)NTOK * DIMV * sizeof(float), hipMemcpyDeviceToDevice, stream);

  for (int l = 0; l < 2; l++) {
    const float* w1l = w1 + (size_t)l * DIMV * 2 * HIDV;
    const float* b1a = b1 + (size_t)l * 2 * HIDV;
    k_transpose<<<dim3(48, 32), 256, 0, stream>>>(wqkv + (size_t)l * DIMV * QKVN, wqkvT,
                                                  DIMV, QKVN, QKVN, 0, DIMV, QKVN, DIMV);
    k_transpose<<<dim3(32, 16), 256, 0, stream>>>(wo + (size_t)l * INNERV * DIMV, woT,
                                                  INNERV, DIMV, DIMV, 0, INNERV, DIMV, INNERV);
    k_transpose<<<dim3(88, 32), 256, 0, stream>>>(w1l, w1T,
                                                  DIMV, HIDV, 2 * HIDV, 0, DIMV, HIDP, DIMV);
    k_transpose<<<dim3(88, 32), 256, 0, stream>>>(w1l, w1T + (size_t)HIDP * DIMV,
                                                  DIMV, HIDV, 2 * HIDV, HIDV, DIMV, HIDP, DIMV);
    k_transpose<<<dim3(32, 88), 256, 0, stream>>>(w2 + (size_t)l * HIDV * DIMV, w2T,
                                                  HIDV, DIMV, DIMV, 0, HIDP, DIMV, HIDP);

    k_shift<<<NTOK, 256, 0, stream>>>(xo, hbuf);
    k_gemm<0><<<dim3(128, 12), 256, 0, stream>>>(hbuf, DIMV, wqkvT, DIMV, qkv, nullptr, nullptr,
                                                 QKVN, DIMV, QKVN);
    k_qkv_post<<<dim3(128, 16), 256, 0, stream>>>(qkv, qsc + l * 64, ksc + l * 64, qarr, karr, vtarr);
    k_attn<<<dim3(128, 16), 256, 0, stream>>>(qarr, karr, vtarr, oarr);
    k_gemm<2><<<dim3(128, 8), 256, 0, stream>>>(oarr, INNERV, woT, INNERV, nullptr, xo, nullptr,
                                                DIMV, INNERV, DIMV);
    k_ln_shift<<<NTOK, 256, 0, stream>>>(xo, hbuf, lng + l * DIMV, lnb + l * DIMV);
    // GEGLU split: gate GEMM (store g+bias), then a GEMM (in-place combine)
    k_gemm<3><<<dim3(128, 22), 256, 0, stream>>>(hbuf, DIMV, w1T + (size_t)HIDP * DIMV, DIMV,
                                                 mlpG, nullptr, b1a + HIDV, HIDV, DIMV, HIDP);
    k_gemm<4><<<dim3(128, 22), 256, 0, stream>>>(hbuf, DIMV, w1T, DIMV,
                                                 mlpG, nullptr, b1a, HIDV, DIMV, HIDP);
    k_gemm<2><<<dim3(128, 8), 256, 0, stream>>>(mlpG, HIDP, w2T, HIDP, nullptr, xo,
                                                b2 + (size_t)l * DIMV, DIMV, HIDP, DIMV);
  }
}